// Round 6
// baseline (474.488 us; speedup 1.0000x reference)
//
#include <hip/hip_runtime.h>

static constexpr int B_    = 64;
static constexpr int N_    = 2048;
static constexpr int DI_   = 8;
static constexpr int O_    = 32;
static constexpr int P_    = 16;
static constexpr int OP_   = O_ * P_;      // 512
static constexpr int M_    = OP_ * B_;     // 32768 s elements
static constexpr int CHUNK_ = 8;
static constexpr int NBLK_  = N_ / CHUNK_; // 256 n-chunks
static constexpr int WSLICE_ = O_ * P_ * DI_;  // 4096 floats per n

// DPP add helper: v + dpp_mov(v). CTRL compile-time (0xB1 quad_perm[1,0,3,2];
// 0x121/2/4/8 = row_ror 1/2/4/8).
template <int CTRL>
__device__ __forceinline__ float dpp_add(float v) {
  int t = __builtin_amdgcn_update_dpp(0, __float_as_int(v), CTRL, 0xf, 0xf, false);
  return v + __int_as_float(t);
}

__device__ __forceinline__ float rfl(float v) {
  return __int_as_float(__builtin_amdgcn_readfirstlane(__float_as_int(v)));
}

// R6: launch-bounds calibration across R3-R5: effective VGPR cap ~= 256 /
// min_waves_per_EU ((1024,4)->64 spilled, (256,4)->64 spilled, (512,2)->96
// no-spill). So: keep R4's proven-clean (512,2) shell (2 blocks/CU resident,
// FETCH 37MB) and remove R4's serializers instead:
//  - 4-slot W ring in LDS (64KB): per 2-nn iter {load tile nn+2 -> compute nn
//    -> ds_write; load nn+3 -> compute nn+1 -> ds_write; ONE barrier}. 4
//    barriers per chunk vs R4's 16; each prefetch covered by ~700cy compute.
//  - v hoisted out of the loop (nn-invariant! was reloaded 8x at the pass-2
//    chain head). Persistent s_r(32)+vv(32), transient pr(32)+wr(8) -> peak
//    ~115 < 128 cap. Tripwire: FETCH>100MB next round = spill, revert hoist.
//  - reduce1 ELIMINATED: epilogue atomicAdds partials into p2[cn & gmask]
//    (16 blocks/address, L2-resident 2MB) -- removes 3 dispatches and
//    3x64MB of spart HBM traffic. p2 double-buffered; zeroed by memset (first)
//    then v_kernel's zero_buf (stream-ordered, graph-replay-safe).
// Unchanged verified machinery: (o,ph) lane remap, LDS-internal XOR swizzle
// (phys chunk g^((g>>4)&7), read (lane*64+(lane&7)*4)^(8pp[+4])), per-nn
// uniform x loads -> readfirstlane -> SGPR FMA operands, in-wave DPP softmax,
// [b][h][lane][4] epilogue indexing (v_kernel idx_src mapping unchanged).
template <int MODE>
__global__ __launch_bounds__(512, 2)
void fused_pass(const float* __restrict__ x, const float* __restrict__ W,
                const float* __restrict__ v_in, float* __restrict__ p2,
                float* __restrict__ rw_out, int gmask) {
  __shared__ __align__(16) float w_lds[4][WSLICE_];   // 64 KB ring
  const int tid  = threadIdx.x;
  const int lane = tid & 63;
  const int wu   = __builtin_amdgcn_readfirstlane(tid >> 6);  // 0..7
  const int o    = lane >> 1;   // 0..31 output capsule
  const int ph   = lane & 1;    // p-half: p = ph*8 + pp
  const int cn   = blockIdx.x >> 1;      // n-chunk 0..255
  const int bh   = blockIdx.x & 1;       // b-half
  const int n0   = cn * CHUNK_;
  const int b0w  = bh * 32 + wu * 4;     // wave's first b (wave-uniform)

  // swizzle: phys chunk = g ^ ((g>>4)&7). Thread stages global chunks tid and
  // tid+512; key identical for both (bit9 doesn't feed bits 4-6), so the
  // second lands at swk + 2048 floats.
  const int swk   = (tid ^ ((tid >> 4) & 7)) * 4;
  const int wbase = lane * 64 + (lane & 7) * 4;

  // hoisted v fragments (nn-invariant): vv[bb][pp], p = ph*8+pp
  float vv[4][8];
  if (MODE != 0) {
    #pragma unroll
    for (int bb = 0; bb < 4; ++bb) {
      const float4* vp =
          (const float4*)(v_in + (size_t)(b0w + bb) * OP_ + lane * 8);
      const float4 a = vp[0], c = vp[1];
      vv[bb][0] = a.x; vv[bb][1] = a.y; vv[bb][2] = a.z; vv[bb][3] = a.w;
      vv[bb][4] = c.x; vv[bb][5] = c.y; vv[bb][6] = c.z; vv[bb][7] = c.w;
    }
  }

  float s_r[4][8];
  #pragma unroll
  for (int bb = 0; bb < 4; ++bb)
    #pragma unroll
    for (int pp = 0; pp < 8; ++pp) s_r[bb][pp] = 0.0f;

  // prologue: stage tiles 0,1 (linear coalesced loads, swizzled ds_writes)
  {
    const float* wp = W + (size_t)n0 * WSLICE_;
    const float4 a0 = *(const float4*)(wp + tid * 4);
    const float4 a1 = *(const float4*)(wp + tid * 4 + 2048);
    const float4 b0 = *(const float4*)(wp + WSLICE_ + tid * 4);
    const float4 b1 = *(const float4*)(wp + WSLICE_ + tid * 4 + 2048);
    *(float4*)&w_lds[0][swk]        = a0;
    *(float4*)&w_lds[0][swk + 2048] = a1;
    *(float4*)&w_lds[1][swk]        = b0;
    *(float4*)&w_lds[1][swk + 2048] = b1;
  }
  __syncthreads();

  #pragma unroll 1
  for (int nn = 0; nn < CHUNK_; nn += 2) {
    #pragma unroll
    for (int u = 0; u < 2; ++u) {
      const int n = n0 + nn + u;
      const float* wbuf = &w_lds[(nn + u) & 3][0];
      const int pf = nn + 2 + u;   // tile to prefetch this half-iter

      // issue prefetch loads EARLY (landing covered by this compute phase)
      float4 c0, c1;
      if (pf < CHUNK_) {
        const float* wp = W + (size_t)(n0 + pf) * WSLICE_;
        c0 = *(const float4*)(wp + tid * 4);
        c1 = *(const float4*)(wp + tid * 4 + 2048);
      }

      // x: wave-uniform 8 floats per b -> SGPRs via readfirstlane
      float xs[4][8];
      #pragma unroll
      for (int bb = 0; bb < 4; ++bb) {
        const float* xp =
            x + (size_t)(b0w + bb) * (N_ * DI_) + (size_t)n * DI_;
        const float4 xa = *(const float4*)xp;
        const float4 xc = *(const float4*)(xp + 4);
        xs[bb][0] = rfl(xa.x); xs[bb][1] = rfl(xa.y);
        xs[bb][2] = rfl(xa.z); xs[bb][3] = rfl(xa.w);
        xs[bb][4] = rfl(xc.x); xs[bb][5] = rfl(xc.y);
        xs[bb][6] = rfl(xc.z); xs[bb][7] = rfl(xc.w);
      }

      // pass 1: predictions
      float pr[4][8];
      #pragma unroll
      for (int pp = 0; pp < 8; ++pp) {
        const float4 w0 = *(const float4*)&wbuf[wbase ^ (8 * pp)];
        const float4 w1 = *(const float4*)&wbuf[wbase ^ (8 * pp + 4)];
        #pragma unroll
        for (int bb = 0; bb < 4; ++bb) {
          float pv = w0.x * xs[bb][0];
          pv = __builtin_fmaf(w0.y, xs[bb][1], pv);
          pv = __builtin_fmaf(w0.z, xs[bb][2], pv);
          pv = __builtin_fmaf(w0.w, xs[bb][3], pv);
          pv = __builtin_fmaf(w1.x, xs[bb][4], pv);
          pv = __builtin_fmaf(w1.y, xs[bb][5], pv);
          pv = __builtin_fmaf(w1.z, xs[bb][6], pv);
          pv = __builtin_fmaf(w1.w, xs[bb][7], pv);
          if (MODE == 0) s_r[bb][pp] += pv;
          else           pr[bb][pp] = pv;
        }
      }

      // pass 2: v-dot (hoisted vv), in-wave DPP softmax, accumulate
      if (MODE != 0) {
        #pragma unroll
        for (int bb = 0; bb < 4; ++bb) {
          float acc = pr[bb][0] * vv[bb][0];
          acc = __builtin_fmaf(pr[bb][1], vv[bb][1], acc);
          acc = __builtin_fmaf(pr[bb][2], vv[bb][2], acc);
          acc = __builtin_fmaf(pr[bb][3], vv[bb][3], acc);
          acc = __builtin_fmaf(pr[bb][4], vv[bb][4], acc);
          acc = __builtin_fmaf(pr[bb][5], vv[bb][5], acc);
          acc = __builtin_fmaf(pr[bb][6], vv[bb][6], acc);
          acc = __builtin_fmaf(pr[bb][7], vv[bb][7], acc);
          // full logit = both p-halves (quad_perm xor1 pairs lanes 2o/2o+1)
          const float full = dpp_add<0xB1>(acc);
          const float e = __expf(full);
          // sum over all 64 lanes = 2*Z[b] (each o counted twice via ph)
          float srow = e;
          srow = dpp_add<0x121>(srow);
          srow = dpp_add<0x122>(srow);
          srow = dpp_add<0x124>(srow);
          srow = dpp_add<0x128>(srow);
          float t16 = srow + __shfl_xor(srow, 16);
          const float S = t16 + __shfl_xor(t16, 32);   // = 2*Z
          const float rw = (2.0f * e) / S;             // e/Z
          #pragma unroll
          for (int pp = 0; pp < 8; ++pp)
            s_r[bb][pp] = __builtin_fmaf(rw, pr[bb][pp], s_r[bb][pp]);
          if (MODE == 2) {
            if (ph == 0)
              rw_out[((size_t)(b0w + bb) * N_ + n) * O_ + o] = rw;
          }
        }
      }

      // publish prefetched tile: slot (pf&3) was last read in the PREVIOUS
      // iteration (before the barrier) -> WAW-safe; next read is after the
      // barrier below -> RAW-safe.
      if (pf < CHUNK_) {
        float* dst = &w_lds[pf & 3][0];
        *(float4*)&dst[swk]        = c0;  // compiler inserts vmcnt wait
        *(float4*)&dst[swk + 2048] = c1;
      }
    }
    __syncthreads();   // ONE barrier per 2 nn
  }

  // epilogue: atomicAdd partials straight into p2 group (cn & gmask).
  // Layout idx(b,o,p) = b*512 + ((p>>2)&1)*256 + (2o+(p>>3))*4 + (p&3)
  // (same as prior spart layout, so v_kernel's idx_src is unchanged).
  {
    float* basep = p2 + (size_t)(cn & gmask) * M_;
    #pragma unroll
    for (int bb = 0; bb < 4; ++bb) {
      float* sp = basep + (size_t)(b0w + bb) * 512 + lane * 4;
      #pragma unroll
      for (int h = 0; h < 2; ++h)
        #pragma unroll
        for (int j = 0; j < 4; ++j)
          atomicAdd(&sp[h * 256 + j], s_r[bb][h * 4 + j]);
    }
  }
}

// sum ngroups (stride M_) + squash; optional v_add; zero zgroups*M_ of
// zero_buf for the NEXT pass (stream-ordered, replay-safe).
// src layout from fused_pass: idx(b,o,p) = b*512 + ((p>>2)&1)*256 +
// (2*o + (p>>3))*4 + (p&3).
__global__ __launch_bounds__(1024)
void v_kernel(const float* __restrict__ src, int ngroups, float scale,
              const float* __restrict__ v_add, float* __restrict__ v_out,
              float* __restrict__ zero_buf, int zgroups) {
  __shared__ float sq[P_ * 65];
  const int t = threadIdx.x;
  const int p = t & 15;
  const int b = t >> 4;
  const int o = blockIdx.x;
  const int q = o * P_ + p;
  const int idx_src = b * 512 + ((p >> 2) & 1) * 256 + (2 * o + (p >> 3)) * 4 +
                      (p & 3);
  float acc = 0.0f;
  for (int g = 0; g < ngroups; ++g)
    acc += src[(size_t)g * M_ + idx_src];
  acc *= scale;
  sq[p * 65 + b] = acc * acc;
  if (zero_buf) {
    for (int g = 0; g < zgroups; ++g)
      zero_buf[(size_t)g * M_ + blockIdx.x * 1024 + t] = 0.0f;
  }
  __syncthreads();
  float s2 = 0.0f;
  #pragma unroll
  for (int pp = 0; pp < P_; ++pp) s2 += sq[pp * 65 + b];
  float sc = (s2 / (1.0f + s2)) / sqrtf(s2 + 1e-7f);
  float v = acc * sc;
  const int idx = b * OP_ + q;   // v layout [b][o][p]
  v_out[idx] = v + (v_add ? v_add[idx] : 0.0f);
}

extern "C" void kernel_launch(void* const* d_in, const int* in_sizes, int n_in,
                              void* d_out, int out_size, void* d_ws, size_t ws_size,
                              hipStream_t stream) {
  (void)in_sizes; (void)n_in; (void)out_size;
  const float* x = (const float*)d_in[0];
  const float* W = (const float*)d_in[1];
  float* out_v  = (float*)d_out;                       // [64][32][16]
  float* out_rw = out_v + (size_t)B_ * O_ * P_;        // [64][2048][32]
  float* vws   = (float*)d_ws;                         // v0
  float* vsum  = vws + M_;                             // v0+v1

  dim3 gF(2 * NBLK_), bF(512), gV(O_), bV(1024);

  const size_t need_big = (size_t)(2 * M_ + 32 * M_) * sizeof(float);
  if (ws_size >= need_big) {
    float* p2A = vsum + M_;           // 16 * M_
    float* p2B = p2A + 16 * M_;       // 16 * M_
    hipMemsetAsync(p2A, 0, (size_t)16 * M_ * sizeof(float), stream);
    fused_pass<0><<<gF, bF, 0, stream>>>(x, W, nullptr, p2A, nullptr, 15);
    v_kernel<<<gV, bV, 0, stream>>>(p2A, 16, 1.0f / 32.0f, nullptr, vws, p2B, 16);
    fused_pass<1><<<gF, bF, 0, stream>>>(x, W, vws, p2B, nullptr, 15);
    v_kernel<<<gV, bV, 0, stream>>>(p2B, 16, 1.0f, vws, vsum, p2A, 16);
    fused_pass<2><<<gF, bF, 0, stream>>>(x, W, vsum, p2A, out_rw, 15);
    v_kernel<<<gV, bV, 0, stream>>>(p2A, 16, 1.0f, nullptr, out_v, nullptr, 0);
  } else {
    // small-ws fallback: single-group accumulation (gmask=0), need 4*M_ floats
    float* sA = vsum + M_;
    float* sB = sA + M_;
    hipMemsetAsync(sA, 0, (size_t)M_ * sizeof(float), stream);
    fused_pass<0><<<gF, bF, 0, stream>>>(x, W, nullptr, sA, nullptr, 0);
    v_kernel<<<gV, bV, 0, stream>>>(sA, 1, 1.0f / 32.0f, nullptr, vws, sB, 1);
    fused_pass<1><<<gF, bF, 0, stream>>>(x, W, vws, sB, nullptr, 0);
    v_kernel<<<gV, bV, 0, stream>>>(sB, 1, 1.0f, vws, vsum, sA, 1);
    fused_pass<2><<<gF, bF, 0, stream>>>(x, W, vsum, sA, out_rw, 0);
    v_kernel<<<gV, bV, 0, stream>>>(sA, 1, 1.0f, nullptr, out_v, nullptr, 0);
  }
}

// Round 7
// 229.806 us; speedup vs baseline: 2.0647x; 2.0647x over previous
//
#include <hip/hip_runtime.h>

static constexpr int B_    = 64;
static constexpr int N_    = 2048;
static constexpr int DI_   = 8;
static constexpr int O_    = 32;
static constexpr int P_    = 16;
static constexpr int OP_   = O_ * P_;      // 512
static constexpr int M_    = OP_ * B_;     // 32768 s elements
static constexpr int CHUNK_ = 8;
static constexpr int NBLK_  = N_ / CHUNK_; // 256 n-chunks
static constexpr int WSLICE_ = O_ * P_ * DI_;  // 4096 floats per n

// DPP add helper: v + dpp_mov(v). CTRL compile-time (0xB1 quad_perm[1,0,3,2];
// 0x121/2/4/8 = row_ror 1/2/4/8).
template <int CTRL>
__device__ __forceinline__ float dpp_add(float v) {
  int t = __builtin_amdgcn_update_dpp(0, __float_as_int(v), CTRL, 0xf, 0xf, false);
  return v + __int_as_float(t);
}

__device__ __forceinline__ float rfl(float v) {
  return __int_as_float(__builtin_amdgcn_readfirstlane(__float_as_int(v)));
}

// R7 = recombination of measured-good pieces only:
//  - R4 shell: (512,2) blocks (the ONLY no-spill config: effective VGPR cap
//    ~= 256/min_waves_per_EU), b-half split, spart-store epilogue + reduce1
//    (R6 proved the atomic epilogue costs ~90us: device-scope atomics to a
//    2MB region serialize at the coherent point, WRITE 49->147MB).
//  - R6 ring-4 W buffer (64KB): ONE barrier per 2 nn (R4 had 2 per nn, each
//    a full vmcnt+lgkm drain); prefetch of tile nn+2/nn+3 covered by a full
//    compute phase. VGPR 112, FETCH 37MB (verified no-spill).
//  - R5 x_lds (8KB, staged once at prologue): per-nn x = ~120cy broadcast
//    ds_read instead of a 300-500cy global round-trip at the chain head.
//    (R5's failure was the (256,4) 64-reg cap spill, not this mechanism.)
// LDS 72KB -> 2 blocks/CU. Unchanged verified machinery: (o,ph) lane remap,
// LDS-internal XOR swizzle (phys chunk g^((g>>4)&7), read
// (lane*64+(lane&7)*4)^(8pp[+4])), readfirstlane x->SGPR FMA operands,
// in-wave DPP softmax, [cn][b][h][lane][4] coalesced epilogue.
template <int MODE, bool ATOMIC>
__global__ __launch_bounds__(512, 2)
void fused_pass(const float* __restrict__ x, const float* __restrict__ W,
                const float* __restrict__ v_in, float* __restrict__ s_out,
                float* __restrict__ rw_out) {
  __shared__ __align__(16) float w_lds[4][WSLICE_];   // 64 KB ring
  __shared__ __align__(16) float x_lds[32 * 64];      // 8 KB: [b_local][n*8+i]
  const int tid  = threadIdx.x;
  const int lane = tid & 63;
  const int wu   = __builtin_amdgcn_readfirstlane(tid >> 6);  // 0..7
  const int o    = lane >> 1;   // 0..31 output capsule
  const int ph   = lane & 1;    // p-half: p = ph*8 + pp
  const int cn   = blockIdx.x >> 1;      // n-chunk 0..255
  const int bh   = blockIdx.x & 1;       // b-half
  const int n0   = cn * CHUNK_;
  const int b0w  = bh * 32 + wu * 4;     // wave's first b (wave-uniform)

  // swizzle: phys chunk = g ^ ((g>>4)&7). Thread stages global chunks tid and
  // tid+512; key identical for both (bit 9 doesn't feed bits 4-6), so the
  // second lands at swk + 2048 floats.
  const int swk   = (tid ^ ((tid >> 4) & 7)) * 4;
  const int wbase = lane * 64 + (lane & 7) * 4;

  // hoisted v fragments (nn-invariant): vv[bb][pp], p = ph*8+pp
  float vv[4][8];
  if (MODE != 0) {
    #pragma unroll
    for (int bb = 0; bb < 4; ++bb) {
      const float4* vp =
          (const float4*)(v_in + (size_t)(b0w + bb) * OP_ + lane * 8);
      const float4 a = vp[0], c = vp[1];
      vv[bb][0] = a.x; vv[bb][1] = a.y; vv[bb][2] = a.z; vv[bb][3] = a.w;
      vv[bb][4] = c.x; vv[bb][5] = c.y; vv[bb][6] = c.z; vv[bb][7] = c.w;
    }
  }

  float s_r[4][8];
  #pragma unroll
  for (int bb = 0; bb < 4; ++bb)
    #pragma unroll
    for (int pp = 0; pp < 8; ++pp) s_r[bb][pp] = 0.0f;

  // prologue: stage x (8KB once; block's 32 b x 64 floats, coalesced) and
  // W tiles 0,1 (linear coalesced loads, swizzled ds_writes).
  {
    const int bl = tid >> 4;    // b_local 0..31
    const int ch = tid & 15;    // float4 chunk within b's 64 floats
    const float4 xv = *(const float4*)(
        x + (size_t)(bh * 32 + bl) * (N_ * DI_) + n0 * DI_ + ch * 4);
    *(float4*)&x_lds[bl * 64 + ch * 4] = xv;

    const float* wp = W + (size_t)n0 * WSLICE_;
    const float4 a0 = *(const float4*)(wp + tid * 4);
    const float4 a1 = *(const float4*)(wp + tid * 4 + 2048);
    const float4 b0 = *(const float4*)(wp + WSLICE_ + tid * 4);
    const float4 b1 = *(const float4*)(wp + WSLICE_ + tid * 4 + 2048);
    *(float4*)&w_lds[0][swk]        = a0;
    *(float4*)&w_lds[0][swk + 2048] = a1;
    *(float4*)&w_lds[1][swk]        = b0;
    *(float4*)&w_lds[1][swk + 2048] = b1;
  }
  __syncthreads();

  #pragma unroll 1
  for (int nn = 0; nn < CHUNK_; nn += 2) {
    #pragma unroll
    for (int u = 0; u < 2; ++u) {
      const int n = n0 + nn + u;
      const float* wbuf = &w_lds[(nn + u) & 3][0];
      const int pf = nn + 2 + u;   // tile to prefetch this half-iter

      // issue prefetch loads EARLY (landing covered by this compute phase)
      float4 c0, c1;
      if (pf < CHUNK_) {
        const float* wp = W + (size_t)(n0 + pf) * WSLICE_;
        c0 = *(const float4*)(wp + tid * 4);
        c1 = *(const float4*)(wp + tid * 4 + 2048);
      }

      // x: broadcast ds_read (~120cy) -> SGPRs via readfirstlane
      float xs[4][8];
      #pragma unroll
      for (int bb = 0; bb < 4; ++bb) {
        const int xb = (wu * 4 + bb) * 64 + (nn + u) * 8;
        const float4 xa = *(const float4*)&x_lds[xb];
        const float4 xc = *(const float4*)&x_lds[xb + 4];
        xs[bb][0] = rfl(xa.x); xs[bb][1] = rfl(xa.y);
        xs[bb][2] = rfl(xa.z); xs[bb][3] = rfl(xa.w);
        xs[bb][4] = rfl(xc.x); xs[bb][5] = rfl(xc.y);
        xs[bb][6] = rfl(xc.z); xs[bb][7] = rfl(xc.w);
      }

      // pass 1: predictions
      float pr[4][8];
      #pragma unroll
      for (int pp = 0; pp < 8; ++pp) {
        const float4 w0 = *(const float4*)&wbuf[wbase ^ (8 * pp)];
        const float4 w1 = *(const float4*)&wbuf[wbase ^ (8 * pp + 4)];
        #pragma unroll
        for (int bb = 0; bb < 4; ++bb) {
          float pv = w0.x * xs[bb][0];
          pv = __builtin_fmaf(w0.y, xs[bb][1], pv);
          pv = __builtin_fmaf(w0.z, xs[bb][2], pv);
          pv = __builtin_fmaf(w0.w, xs[bb][3], pv);
          pv = __builtin_fmaf(w1.x, xs[bb][4], pv);
          pv = __builtin_fmaf(w1.y, xs[bb][5], pv);
          pv = __builtin_fmaf(w1.z, xs[bb][6], pv);
          pv = __builtin_fmaf(w1.w, xs[bb][7], pv);
          if (MODE == 0) s_r[bb][pp] += pv;
          else           pr[bb][pp] = pv;
        }
      }

      // pass 2: v-dot (hoisted vv), in-wave DPP softmax, accumulate
      if (MODE != 0) {
        #pragma unroll
        for (int bb = 0; bb < 4; ++bb) {
          float acc = pr[bb][0] * vv[bb][0];
          acc = __builtin_fmaf(pr[bb][1], vv[bb][1], acc);
          acc = __builtin_fmaf(pr[bb][2], vv[bb][2], acc);
          acc = __builtin_fmaf(pr[bb][3], vv[bb][3], acc);
          acc = __builtin_fmaf(pr[bb][4], vv[bb][4], acc);
          acc = __builtin_fmaf(pr[bb][5], vv[bb][5], acc);
          acc = __builtin_fmaf(pr[bb][6], vv[bb][6], acc);
          acc = __builtin_fmaf(pr[bb][7], vv[bb][7], acc);
          // full logit = both p-halves (quad_perm xor1 pairs lanes 2o/2o+1)
          const float full = dpp_add<0xB1>(acc);
          const float e = __expf(full);
          // sum over all 64 lanes = 2*Z[b] (each o counted twice via ph)
          float srow = e;
          srow = dpp_add<0x121>(srow);
          srow = dpp_add<0x122>(srow);
          srow = dpp_add<0x124>(srow);
          srow = dpp_add<0x128>(srow);
          float t16 = srow + __shfl_xor(srow, 16);
          const float S = t16 + __shfl_xor(t16, 32);   // = 2*Z
          const float rw = (2.0f * e) / S;             // e/Z
          #pragma unroll
          for (int pp = 0; pp < 8; ++pp)
            s_r[bb][pp] = __builtin_fmaf(rw, pr[bb][pp], s_r[bb][pp]);
          if (MODE == 2) {
            if (ph == 0)
              rw_out[((size_t)(b0w + bb) * N_ + n) * O_ + o] = rw;
          }
        }
      }

      // publish prefetched tile: slot (pf&3)'s previous tile (pf-4) was last
      // read in iteration nn-2 (ended with a barrier) -> WAW-safe; readers of
      // tile pf start after the barrier below -> RAW-safe.
      if (pf < CHUNK_) {
        float* dst = &w_lds[pf & 3][0];
        *(float4*)&dst[swk]        = c0;  // compiler inserts vmcnt wait
        *(float4*)&dst[swk + 2048] = c1;
      }
    }
    __syncthreads();   // ONE barrier per 2 nn
  }

  // epilogue, spart layout [cn][b][h][lane][4]: each float4 store is
  // base + lane*16B -> contiguous 1KB per instr.
  if (ATOMIC) {
    #pragma unroll
    for (int bb = 0; bb < 4; ++bb) {
      #pragma unroll
      for (int h = 0; h < 2; ++h)
        #pragma unroll
        for (int j = 0; j < 4; ++j)
          atomicAdd(&s_out[(size_t)(b0w + bb) * 512 + h * 256 + lane * 4 + j],
                    s_r[bb][h * 4 + j]);
    }
  } else {
    #pragma unroll
    for (int bb = 0; bb < 4; ++bb) {
      float* sp = s_out + (size_t)cn * M_ + (size_t)(b0w + bb) * 512 + lane * 4;
      float4 st0, st1;
      st0.x = s_r[bb][0]; st0.y = s_r[bb][1]; st0.z = s_r[bb][2]; st0.w = s_r[bb][3];
      st1.x = s_r[bb][4]; st1.y = s_r[bb][5]; st1.z = s_r[bb][6]; st1.w = s_r[bb][7];
      *(float4*)sp = st0;
      *(float4*)(sp + 256) = st1;
    }
  }
}

// stage-1 reduction: P[K][M_] -> P2[16][M_]; grid 16 groups x 16 m-chunks.
// (element-wise over flat M_, layout-agnostic)
__global__ __launch_bounds__(1024)
void reduce1(const float* __restrict__ spart, float* __restrict__ p2, int K) {
  const int g  = blockIdx.x >> 4;
  const int mc = blockIdx.x & 15;
  const int kpg = K >> 4;
  const int m0 = mc * 2048 + threadIdx.x;
  float a0 = 0.0f, a1 = 0.0f;
  const float* p = spart + (size_t)(g * kpg) * M_;
  for (int k = 0; k < kpg; ++k) {
    a0 += p[(size_t)k * M_ + m0];
    a1 += p[(size_t)k * M_ + m0 + 1024];
  }
  p2[(size_t)g * M_ + m0]        = a0;
  p2[(size_t)g * M_ + m0 + 1024] = a1;
}

// sum ngroups (stride M_) + squash; optional v_add / zero_buf.
// src layout from fused_pass: idx(b,o,p) = b*512 + ((p>>2)&1)*256 +
// (2*o + (p>>3))*4 + (p&3).
__global__ __launch_bounds__(1024)
void v_kernel(const float* __restrict__ src, int ngroups, float scale,
              const float* __restrict__ v_add, float* __restrict__ v_out,
              float* __restrict__ zero_buf) {
  __shared__ float sq[P_ * 65];
  const int t = threadIdx.x;
  const int p = t & 15;
  const int b = t >> 4;
  const int o = blockIdx.x;
  const int q = o * P_ + p;
  const int idx_src = b * 512 + ((p >> 2) & 1) * 256 + (2 * o + (p >> 3)) * 4 +
                      (p & 3);
  float acc = 0.0f;
  for (int g = 0; g < ngroups; ++g)
    acc += src[(size_t)g * M_ + idx_src];
  acc *= scale;
  sq[p * 65 + b] = acc * acc;
  if (zero_buf) zero_buf[blockIdx.x * 1024 + t] = 0.0f;
  __syncthreads();
  float s2 = 0.0f;
  #pragma unroll
  for (int pp = 0; pp < P_; ++pp) s2 += sq[pp * 65 + b];
  float sc = (s2 / (1.0f + s2)) / sqrtf(s2 + 1e-7f);
  float v = acc * sc;
  const int idx = b * OP_ + q;   // v layout [b][o][p]
  v_out[idx] = v + (v_add ? v_add[idx] : 0.0f);
}

extern "C" void kernel_launch(void* const* d_in, const int* in_sizes, int n_in,
                              void* d_out, int out_size, void* d_ws, size_t ws_size,
                              hipStream_t stream) {
  (void)in_sizes; (void)n_in; (void)out_size;
  const float* x = (const float*)d_in[0];
  const float* W = (const float*)d_in[1];
  float* out_v  = (float*)d_out;                       // [64][32][16]
  float* out_rw = out_v + (size_t)B_ * O_ * P_;        // [64][2048][32]
  float* vws   = (float*)d_ws;                         // v0
  float* vsum  = vws + M_;                             // v0+v1
  float* p2    = vsum + M_;                            // 16 * M_
  float* spart = p2 + 16 * M_;                         // NBLK_ * M_

  const size_t need = (size_t)(2 * M_ + 16 * M_ + (size_t)NBLK_ * M_) * 4;

  dim3 gF(2 * NBLK_), bF(512), gV(O_), bV(1024), gR(256), bR(1024);
  if (ws_size >= need) {
    fused_pass<0, false><<<gF, bF, 0, stream>>>(x, W, nullptr, spart, nullptr);
    reduce1<<<gR, bR, 0, stream>>>(spart, p2, NBLK_);
    v_kernel<<<gV, bV, 0, stream>>>(p2, 16, 1.0f / 32.0f, nullptr, vws, nullptr);
    fused_pass<1, false><<<gF, bF, 0, stream>>>(x, W, vws, spart, nullptr);
    reduce1<<<gR, bR, 0, stream>>>(spart, p2, NBLK_);
    v_kernel<<<gV, bV, 0, stream>>>(p2, 16, 1.0f, vws, vsum, nullptr);
    fused_pass<2, false><<<gF, bF, 0, stream>>>(x, W, vsum, spart, out_rw);
    reduce1<<<gR, bR, 0, stream>>>(spart, p2, NBLK_);
    v_kernel<<<gV, bV, 0, stream>>>(p2, 16, 1.0f, nullptr, out_v, nullptr);
  } else {
    // atomic fallback for small ws
    float* sAb = p2;
    float* sBb = sAb + M_;
    hipMemsetAsync(sAb, 0, (size_t)M_ * sizeof(float), stream);
    fused_pass<0, true><<<gF, bF, 0, stream>>>(x, W, nullptr, sAb, nullptr);
    v_kernel<<<gV, bV, 0, stream>>>(sAb, 1, 1.0f / 32.0f, nullptr, vws, sBb);
    fused_pass<1, true><<<gF, bF, 0, stream>>>(x, W, vws, sBb, nullptr);
    v_kernel<<<gV, bV, 0, stream>>>(sBb, 1, 1.0f, vws, vsum, sAb);
    fused_pass<2, true><<<gF, bF, 0, stream>>>(x, W, vsum, sAb, out_rw);
    v_kernel<<<gV, bV, 0, stream>>>(sAb, 1, 1.0f, nullptr, out_v, nullptr);
  }
}